// Round 15
// baseline (81.265 us; speedup 1.0000x reference)
//
#include <hip/hip_runtime.h>
#include <hip/hip_bf16.h>
#include <hip/hip_fp8.h>

// ContrastiveLoss fused kernel for MI355X (gfx950).
//
// Math reduction (T=0.5):
//   f = x / max(||x||, 1e-8)   (rows)
//   s_ij = f_i . f_j
//   den_i = sum_{j: label_j != label_i} exp(2 s_ij)
//   loss  = sum_i [ c_i * log(den_i) - sum_{j same label, j != i} 2 s_ij ]
//           / (sum_i c_i + 1e-5),   c_i = count(label_i) - 1
//
// N=4096, D=512, labels in [0,100).
//
// Round 15: SINGLE LAUNCH, PRODUCER-CONSUMER, NO GRID BARRIER.
// R14 budget: kernel work sums to ~10-13 us but total is 36.8 -> the
// dominant term is the 2 inter-kernel graph boundaries (~5-10 us each)
// + ramps. R12 (cooperative: silently no-ops under capture) and R13
// (grid barrier: 180 us convergence idle) failed for structural
// reasons; this design has ZERO convergence points:
//  - ticket production: first 256 blocks-to-run (atomic ticket) each
//    normalize one 16-row group -> fp8 fragment-major G + lab8 + den/pos
//    zeros; publish via __threadfence (buffer_wbl2) + release-store of
//    ready[g]. Ticket holders are running blocks -> no deadlock.
//  - consumers poll only their 16 group flags (relaxed + s_sleep), one
//    acquire __threadfence (buffer_inv), then R14's proven whole-tile
//    zero-barrier fp8 k2 body verbatim (symmetric 528 tile-pairs).
//  - last-done block (atomic counter) runs finalize inline, writes out.
// Publish mechanism identical to R13's (numerically proven: absmax 0).

typedef float floatx4 __attribute__((ext_vector_type(4)));
typedef long lng2 __attribute__((ext_vector_type(2)));
typedef unsigned int u32;
typedef unsigned char u8;

#define N_ROWS 4096
#define DIM 512
#define GRPB 8192              // bytes per 16-row fp8 fragment group (16*512)
#define NGROUP 256             // 16-row production groups
#define EPS_NORM 1e-8f
#define EPS_DEN 1e-5f
#define TI 128                 // tile size (rows and cols)
#define NT (N_ROWS / TI)       // 32 tiles
#define NPAIR (NT * (NT + 1) / 2)   // 528 blocks
#define NSLAB 8                // 8 slabs of 16 j-rows per tile

static __device__ inline void load_lds16(const char* g, char* l) {
  __builtin_amdgcn_global_load_lds(
      (const __attribute__((address_space(1))) void*)g,
      (__attribute__((address_space(3))) void*)l, 16, 0, 0);
}

__global__ __launch_bounds__(256, 2) void mono(
    const float* __restrict__ x, const int* __restrict__ labels,
    u8* __restrict__ G, u8* __restrict__ lab8,
    float* __restrict__ den, float* __restrict__ pos,
    int* ctrl, float* __restrict__ out) {
  __shared__ u8 Bsh[64 * 1024];          // whole B tile: 64 chunks x 1 KB
  __shared__ int labj_sh[TI];
  __shared__ float colden[TI], colpos[TI];
  __shared__ int hist[128];
  __shared__ float sred[8];
  __shared__ int stick;

  const char* Gb = (const char*)G;
  char* bshb = (char*)Bsh;

  int* ready = ctrl;           // [NGROUP] flags, zeroed by hipMemsetAsync
  int* ticket = ctrl + NGROUP;
  int* done = ctrl + NGROUP + 1;

  const int tid = threadIdx.x;
  const int wv = tid >> 6;
  const int lane = tid & 63;
  const int l15 = lane & 15;
  const int kg4 = lane >> 4;              // 0..3 (16-col groups)

  // ============ production: ticket-holders normalize one 16-row group ======
  if (tid == 0) stick = atomicAdd(ticket, 1);
  __syncthreads();
  const int tk = stick;
  if (tk < NGROUP) {
    // G layout (fp8): group g = row>>4 (8192 B), kt-pair = kt>>1 (1024 B);
    // consumer lane l = kq*16 + (row&15) holds fragment of kt at byte
    // l*16 + (kt&1)*8, covering k = kt*32 + kq*8 .. +8.
#pragma unroll
    for (int rr = 0; rr < 4; ++rr) {
      const int row = tk * 16 + rr * 4 + wv;
      const float4* src = reinterpret_cast<const float4*>(x + (size_t)row * DIM);
      float4 v0 = src[lane * 2];
      float4 v1 = src[lane * 2 + 1];
      float ss = v0.x*v0.x + v0.y*v0.y + v0.z*v0.z + v0.w*v0.w
               + v1.x*v1.x + v1.y*v1.y + v1.z*v1.z + v1.w*v1.w;
#pragma unroll
      for (int m = 1; m < 64; m <<= 1) ss += __shfl_xor(ss, m, 64);
      float scale = 1.f / fmaxf(sqrtf(ss), EPS_NORM);

      u32 lo = ((u32)__hip_fp8_e4m3(v0.x * scale).__x)
             | ((u32)__hip_fp8_e4m3(v0.y * scale).__x << 8)
             | ((u32)__hip_fp8_e4m3(v0.z * scale).__x << 16)
             | ((u32)__hip_fp8_e4m3(v0.w * scale).__x << 24);
      u32 hi = ((u32)__hip_fp8_e4m3(v1.x * scale).__x)
             | ((u32)__hip_fp8_e4m3(v1.y * scale).__x << 8)
             | ((u32)__hip_fp8_e4m3(v1.z * scale).__x << 16)
             | ((u32)__hip_fp8_e4m3(v1.w * scale).__x << 24);
      uint2 o; o.x = lo; o.y = hi;

      const int kt = lane >> 2;
      const int kq = lane & 3;
      char* dst = (char*)G + (size_t)(row >> 4) * GRPB + (kt >> 1) * 1024
                + (kq * 16 + (row & 15)) * 16 + (kt & 1) * 8;
      *reinterpret_cast<uint2*>(dst) = o;

      if (lane == 0) { den[row] = 0.f; pos[row] = 0.f; }
      if (lane == 1) lab8[row] = (u8)labels[row];
    }
    __syncthreads();           // all 16 rows' stores issued+retired (vmcnt drain)
    if (tid == 0) {
      __threadfence();         // release: write back G/lab8/den/pos lines
      __hip_atomic_store(&ready[tk], 1, __ATOMIC_RELEASE,
                         __HIP_MEMORY_SCOPE_AGENT);
    }
  }

  // ============ consumption: decode pair (ti, tj), wait for its groups =====
  int b = blockIdx.x;
  int ti = 0, rem = NT;
  while (b >= rem) { b -= rem; ++ti; --rem; }
  const int tj = ti + b;
  const bool diag = (ti == tj);

  const int ib = ti * TI;
  const int jb = tj * TI;

  if (tid == 0) {
#pragma unroll
    for (int g = 0; g < 8; ++g) {
      while (__hip_atomic_load(&ready[ti * 8 + g], __ATOMIC_RELAXED,
                               __HIP_MEMORY_SCOPE_AGENT) == 0)
        __builtin_amdgcn_s_sleep(2);
      while (__hip_atomic_load(&ready[tj * 8 + g], __ATOMIC_RELAXED,
                               __HIP_MEMORY_SCOPE_AGENT) == 0)
        __builtin_amdgcn_s_sleep(2);
    }
    __threadfence();           // acquire: invalidate stale local cache lines
  }
  __syncthreads();

  // stage the WHOLE B tile (64 KB = 64 chunks); wave wv stages chunks
  // wv*16 .. wv*16+15. Contiguous 1 KB src AND dst.
#pragma unroll
  for (int c = 0; c < 16; ++c) {
    const int chunk = wv * 16 + c;
    load_lds16(Gb + (size_t)(tj * 8 + (chunk >> 3)) * GRPB
                  + (chunk & 7) * 1024 + lane * 16,
               bshb + chunk * 1024 + lane * 16);
  }
  if (tid < TI) {
    labj_sh[tid] = lab8[jb + tid];
    colden[tid] = 0.f;
    colpos[tid] = 0.f;
  }

  // A fragments: 32 rows/wave = 2 fp8 fragment groups -> 64 VGPRs.
  long a0[16], a1[16];
  {
    const char* ab0 = Gb + (size_t)(ti * 8 + wv * 2) * GRPB + lane * 16;
    const char* ab1 = ab0 + GRPB;
#pragma unroll
    for (int q = 0; q < 8; ++q) {
      lng2 v0 = *reinterpret_cast<const lng2*>(ab0 + q * 1024);
      lng2 v1 = *reinterpret_cast<const lng2*>(ab1 + q * 1024);
      a0[2 * q] = v0.x; a0[2 * q + 1] = v0.y;
      a1[2 * q] = v1.x; a1[2 * q + 1] = v1.y;
    }
  }
#pragma unroll
  for (int kt = 0; kt < 16; ++kt) {
    asm volatile("" : "+v"(a0[kt]));
    asm volatile("" : "+v"(a1[kt]));
  }

  // C/D layout (verified gfx950, dtype-independent): col = lane&15 (j),
  // row = kg4*4 + r (i). lane's 8 output rows: i_base + s*16 + r.
  const int i_base = ib + wv * 32 + kg4 * 4;
  const u32 labp0 = *reinterpret_cast<const u32*>(lab8 + i_base);
  const u32 labp1 = *reinterpret_cast<const u32*>(lab8 + i_base + 16);

  float den_acc[2][4] = {{0.f,0.f,0.f,0.f},{0.f,0.f,0.f,0.f}};
  float pos_acc[2][4] = {{0.f,0.f,0.f,0.f},{0.f,0.f,0.f,0.f}};

  __syncthreads();   // ONE drain: whole tile staged, labels + col accs ready

  // barrier-free main loop: 8 slabs x 32 MFMA + epilogue
#pragma unroll
  for (int t = 0; t < NSLAB; ++t) {
    const int jrow = jb + t * 16 + l15;
    const int labj = labj_sh[t * 16 + l15];

    floatx4 acc0 = {0.f,0.f,0.f,0.f};
    floatx4 acc1 = {0.f,0.f,0.f,0.f};
    const char* bbase = bshb + t * 8192 + lane * 16;
#pragma unroll
    for (int q = 0; q < 8; ++q) {
      lng2 b2 = *reinterpret_cast<const lng2*>(bbase + q * 1024);
      acc0 = __builtin_amdgcn_mfma_f32_16x16x32_fp8_fp8(a0[2*q],   b2.x, acc0, 0, 0, 0);
      acc1 = __builtin_amdgcn_mfma_f32_16x16x32_fp8_fp8(a1[2*q],   b2.x, acc1, 0, 0, 0);
      acc0 = __builtin_amdgcn_mfma_f32_16x16x32_fp8_fp8(a0[2*q+1], b2.y, acc0, 0, 0, 0);
      acc1 = __builtin_amdgcn_mfma_f32_16x16x32_fp8_fp8(a1[2*q+1], b2.y, acc1, 0, 0, 0);
    }

    float cd = 0.f, cp = 0.f;   // col partials for this 16-j slab
#pragma unroll
    for (int s = 0; s < 2; ++s) {
      floatx4 av = s ? acc1 : acc0;
      const u32 labp = s ? labp1 : labp0;
#pragma unroll
      for (int r = 0; r < 4; ++r) {
        const int labi = (int)((labp >> (8 * r)) & 255u);
        const int irow = i_base + s * 16 + r;
        float s2 = 2.f * av[r];
        float e = __expf(s2);
        bool sm = (labj == labi);
        float dv = sm ? 0.f : e;
        float pv = (sm && (jrow != irow)) ? s2 : 0.f;
        den_acc[s][r] += dv;
        pos_acc[s][r] += pv;
        cd += dv; cp += pv;
      }
    }
    if (!diag) {
      cd += __shfl_xor(cd, 16, 64); cd += __shfl_xor(cd, 32, 64);
      cp += __shfl_xor(cp, 16, 64); cp += __shfl_xor(cp, 32, 64);
      if (kg4 == 0) {
        atomicAdd(&colden[t * 16 + l15], cd);
        atomicAdd(&colpos[t * 16 + l15], cp);
      }
    }
  }

  // row path: reduce across 16 cols (lanes with same kg4), 1 atomic/row
#pragma unroll
  for (int s = 0; s < 2; ++s)
#pragma unroll
    for (int r = 0; r < 4; ++r) {
      float dd = den_acc[s][r], pp = pos_acc[s][r];
#pragma unroll
      for (int m = 1; m < 16; m <<= 1) {
        dd += __shfl_xor(dd, m, 64);
        pp += __shfl_xor(pp, m, 64);
      }
      if (l15 == 0) {
        atomicAdd(&den[i_base + s * 16 + r], dd);
        atomicAdd(&pos[i_base + s * 16 + r], pp);
      }
    }

  // col path flush (off-diagonal): one atomic per col
  if (!diag) {
    __syncthreads();   // all waves' LDS col atomics done
    if (tid < TI) {
      atomicAdd(&den[jb + tid], colden[tid]);
      atomicAdd(&pos[jb + tid], colpos[tid]);
    }
  }

  // ============ finalize: last-done block computes the scalar ==============
  __syncthreads();             // vmcnt drain: this block's atomics performed
  if (tid == 0) stick = atomicAdd(done, 1);
  __syncthreads();
  if (stick == NPAIR - 1) {
    if (tid == 0) __threadfence();   // acquire: invalidate stale den/pos lines
    if (tid < 128) hist[tid] = 0;
    __syncthreads();
    for (int i = tid; i < N_ROWS; i += 256) atomicAdd(&hist[labels[i]], 1);
    __syncthreads();

    float num = 0.f, nnz = 0.f;
    for (int i = tid; i < N_ROWS; i += 256) {
      int c = hist[labels[i]] - 1;
      num += (float)c * logf(den[i]) - pos[i];
      nnz += (float)c;
    }
#pragma unroll
    for (int m = 1; m < 64; m <<= 1) {
      num += __shfl_xor(num, m, 64);
      nnz += __shfl_xor(nnz, m, 64);
    }
    if ((tid & 63) == 0) { sred[wv] = num; sred[4 + wv] = nnz; }
    __syncthreads();
    if (tid == 0) {
      float tn = sred[0] + sred[1] + sred[2] + sred[3];
      float tz = sred[4] + sred[5] + sred[6] + sred[7];
      out[0] = tn / (tz + EPS_DEN);
    }
  }
}

extern "C" void kernel_launch(void* const* d_in, const int* in_sizes, int n_in,
                              void* d_out, int out_size, void* d_ws, size_t ws_size,
                              hipStream_t stream) {
  const float* x = (const float*)d_in[0];
  const int* labels = (const int*)d_in[1];

  // ws: G fp8 (2MB) | den f32[4096] | pos f32[4096] | lab8 u8[4096]
  //   | ctrl i32[NGROUP + 2]  (ready[256], ticket, done)
  u8* G = (u8*)d_ws;
  float* den = (float*)((char*)d_ws + (size_t)N_ROWS * DIM);
  float* pos = den + N_ROWS;
  u8* lab8 = (u8*)(pos + N_ROWS);
  int* ctrl = (int*)(lab8 + N_ROWS);
  float* out = (float*)d_out;

  hipMemsetAsync(ctrl, 0, (NGROUP + 2) * sizeof(int), stream);
  hipLaunchKernelGGL(mono, dim3(NPAIR), dim3(256), 0, stream,
                     x, labels, G, lab8, den, pos, ctrl, out);
}

// Round 16
// 48.964 us; speedup vs baseline: 1.6597x; 1.6597x over previous
//
#include <hip/hip_runtime.h>
#include <hip/hip_bf16.h>
#include <hip/hip_fp8.h>

// ContrastiveLoss fused kernel for MI355X (gfx950).
//
// Math reduction (T=0.5):
//   f = x / max(||x||, 1e-8)   (rows)
//   s_ij = f_i . f_j
//   den_i = sum_{j: label_j != label_i} exp(2 s_ij)
//   loss  = sum_i [ c_i * log(den_i) - sum_{j same label, j != i} 2 s_ij ]
//           / (sum_i c_i + 1e-5),   c_i = count(label_i) - 1
//
// N=4096, D=512, labels in [0,100).
//
// Round 16: R14 structure (best: 36.8 us) minus one kernel boundary and
// minus the residency tail. Grid-fusion is dead (R12 cooperative no-op,
// R13 grid-barrier 180 us, R15 producer-consumer 81 us) -- boundaries
// beat intra-kernel dataflow on this chip. Changes vs R14:
//  1. finalize folded into k2: per-block __threadfence + atomicAdd(done);
//     the 512th block acquires and finalizes inline reading den/pos via
//     atomicAdd(p,0.f) device-coherent reads (pattern numerically proven
//     in R13/R14/R15). Saves k3a dispatch + boundary.
//  2. grid 512 (2 blocks/CU, all co-resident): blocks 0..15 take a 2nd
//     pair via u += 512 -- no 3rd residency round, no extra ramp.
// k2 core (fp8 e4m3 16x16x32, whole 64 KB B tile staged once, ONE
// syncthreads, zero-barrier main loop, symmetric row+col accumulation)
// is bit-identical to R14. k1 unchanged.

typedef float floatx4 __attribute__((ext_vector_type(4)));
typedef long lng2 __attribute__((ext_vector_type(2)));
typedef unsigned int u32;
typedef unsigned char u8;

#define N_ROWS 4096
#define DIM 512
#define GRPB 8192              // bytes per 16-row fp8 fragment group (16*512)
#define EPS_NORM 1e-8f
#define EPS_DEN 1e-5f
#define TI 128                 // tile size (rows and cols)
#define NT (N_ROWS / TI)       // 32 tiles
#define NPAIR (NT * (NT + 1) / 2)   // 528 pairs
#define NSLAB 8                // 8 slabs of 16 j-rows per tile
#define GRID 512

static __device__ inline void load_lds16(const char* g, char* l) {
  __builtin_amdgcn_global_load_lds(
      (const __attribute__((address_space(1))) void*)g,
      (__attribute__((address_space(3))) void*)l, 16, 0, 0);
}

// wave-per-row normalize + fp8 pack, fragment-major store; grid 1024 x 256.
// G layout (fp8): group g = row>>4 (8192 B), kt-pair p = kt>>1 (1024 B);
// consumer lane l = kq*16 + (row&15) holds fragment of kt at byte
// l*16 + (kt&1)*8, covering k = kt*32 + kq*8 .. +8.
__global__ void k1_normalize(const float* __restrict__ x,
                             const int* __restrict__ labels,
                             u8* __restrict__ G, u8* __restrict__ lab8,
                             float* __restrict__ den, float* __restrict__ pos,
                             float* __restrict__ acc2, int* __restrict__ done) {
  const int row = blockIdx.x * 4 + (threadIdx.x >> 6);
  const int lane = threadIdx.x & 63;
  const float4* src = reinterpret_cast<const float4*>(x + (size_t)row * DIM);
  float4 v0 = src[lane * 2];
  float4 v1 = src[lane * 2 + 1];
  float ss = v0.x*v0.x + v0.y*v0.y + v0.z*v0.z + v0.w*v0.w
           + v1.x*v1.x + v1.y*v1.y + v1.z*v1.z + v1.w*v1.w;
#pragma unroll
  for (int m = 1; m < 64; m <<= 1) ss += __shfl_xor(ss, m, 64);
  float scale = 1.f / fmaxf(sqrtf(ss), EPS_NORM);

  u32 lo = ((u32)__hip_fp8_e4m3(v0.x * scale).__x)
         | ((u32)__hip_fp8_e4m3(v0.y * scale).__x << 8)
         | ((u32)__hip_fp8_e4m3(v0.z * scale).__x << 16)
         | ((u32)__hip_fp8_e4m3(v0.w * scale).__x << 24);
  u32 hi = ((u32)__hip_fp8_e4m3(v1.x * scale).__x)
         | ((u32)__hip_fp8_e4m3(v1.y * scale).__x << 8)
         | ((u32)__hip_fp8_e4m3(v1.z * scale).__x << 16)
         | ((u32)__hip_fp8_e4m3(v1.w * scale).__x << 24);
  uint2 o; o.x = lo; o.y = hi;

  const int kt = lane >> 2;
  const int kq = lane & 3;
  char* dst = (char*)G + (size_t)(row >> 4) * GRPB + (kt >> 1) * 1024
            + (kq * 16 + (row & 15)) * 16 + (kt & 1) * 8;
  *reinterpret_cast<uint2*>(dst) = o;

  if (lane == 0) { den[row] = 0.f; pos[row] = 0.f; }
  if (lane == 1) lab8[row] = (u8)labels[row];
  if (blockIdx.x == 0 && threadIdx.x == 0) {
    acc2[0] = 0.f; acc2[1] = 0.f; done[0] = 0;
  }
}

// fused fp8 sim-GEMM + symmetric reduction + inline finalize (last block).
__global__ __launch_bounds__(256, 2) void k2_fused(
    const u8* __restrict__ G, const u8* __restrict__ lab8,
    const int* __restrict__ labels,
    float* __restrict__ den, float* __restrict__ pos,
    float* acc2, int* done, float* __restrict__ out) {
  __shared__ u8 Bsh[64 * 1024];          // whole B tile: 64 chunks x 1 KB
  __shared__ int labj_sh[TI];
  __shared__ float colden[TI], colpos[TI];
  __shared__ int hist[128];
  __shared__ float sred[8];
  __shared__ int stick;

  const char* Gb = (const char*)G;
  char* bshb = (char*)Bsh;

  const int tid = threadIdx.x;
  const int wv = tid >> 6;
  const int lane = tid & 63;
  const int l15 = lane & 15;
  const int kg4 = lane >> 4;              // 0..3 (16-col groups)

  for (int u = blockIdx.x; u < NPAIR; u += GRID) {
    // decode pair (ti, tj), ti <= tj
    int b = u;
    int ti = 0, rem = NT;
    while (b >= rem) { b -= rem; ++ti; --rem; }
    const int tj = ti + b;
    const bool diag = (ti == tj);

    const int ib = ti * TI;
    const int jb = tj * TI;

    if (u != (int)blockIdx.x) __syncthreads();  // 2nd pair: LDS safe to reuse

    // stage the WHOLE B tile (64 KB = 64 chunks); wave wv stages chunks
    // wv*16 .. wv*16+15. Contiguous 1 KB src AND dst.
#pragma unroll
    for (int c = 0; c < 16; ++c) {
      const int chunk = wv * 16 + c;
      load_lds16(Gb + (size_t)(tj * 8 + (chunk >> 3)) * GRPB
                    + (chunk & 7) * 1024 + lane * 16,
                 bshb + chunk * 1024 + lane * 16);
    }
    if (tid < TI) {
      labj_sh[tid] = lab8[jb + tid];
      colden[tid] = 0.f;
      colpos[tid] = 0.f;
    }

    // A fragments: 32 rows/wave = 2 fp8 fragment groups -> 64 VGPRs.
    long a0[16], a1[16];
    {
      const char* ab0 = Gb + (size_t)(ti * 8 + wv * 2) * GRPB + lane * 16;
      const char* ab1 = ab0 + GRPB;
#pragma unroll
      for (int q = 0; q < 8; ++q) {
        lng2 v0 = *reinterpret_cast<const lng2*>(ab0 + q * 1024);
        lng2 v1 = *reinterpret_cast<const lng2*>(ab1 + q * 1024);
        a0[2 * q] = v0.x; a0[2 * q + 1] = v0.y;
        a1[2 * q] = v1.x; a1[2 * q + 1] = v1.y;
      }
    }
#pragma unroll
    for (int kt = 0; kt < 16; ++kt) {
      asm volatile("" : "+v"(a0[kt]));
      asm volatile("" : "+v"(a1[kt]));
    }

    // C/D layout (verified gfx950, dtype-independent): col = lane&15 (j),
    // row = kg4*4 + r (i). lane's 8 output rows: i_base + s*16 + r.
    const int i_base = ib + wv * 32 + kg4 * 4;
    const u32 labp0 = *reinterpret_cast<const u32*>(lab8 + i_base);
    const u32 labp1 = *reinterpret_cast<const u32*>(lab8 + i_base + 16);

    float den_acc[2][4] = {{0.f,0.f,0.f,0.f},{0.f,0.f,0.f,0.f}};
    float pos_acc[2][4] = {{0.f,0.f,0.f,0.f},{0.f,0.f,0.f,0.f}};

    __syncthreads();   // ONE drain: tile staged, labels + col accs ready

    // barrier-free main loop: 8 slabs x 32 MFMA + epilogue
#pragma unroll
    for (int t = 0; t < NSLAB; ++t) {
      const int jrow = jb + t * 16 + l15;
      const int labj = labj_sh[t * 16 + l15];

      floatx4 acc0 = {0.f,0.f,0.f,0.f};
      floatx4 acc1 = {0.f,0.f,0.f,0.f};
      const char* bbase = bshb + t * 8192 + lane * 16;
#pragma unroll
      for (int q = 0; q < 8; ++q) {
        lng2 b2 = *reinterpret_cast<const lng2*>(bbase + q * 1024);
        acc0 = __builtin_amdgcn_mfma_f32_16x16x32_fp8_fp8(a0[2*q],   b2.x, acc0, 0, 0, 0);
        acc1 = __builtin_amdgcn_mfma_f32_16x16x32_fp8_fp8(a1[2*q],   b2.x, acc1, 0, 0, 0);
        acc0 = __builtin_amdgcn_mfma_f32_16x16x32_fp8_fp8(a0[2*q+1], b2.y, acc0, 0, 0, 0);
        acc1 = __builtin_amdgcn_mfma_f32_16x16x32_fp8_fp8(a1[2*q+1], b2.y, acc1, 0, 0, 0);
      }

      float cd = 0.f, cp = 0.f;   // col partials for this 16-j slab
#pragma unroll
      for (int s = 0; s < 2; ++s) {
        floatx4 av = s ? acc1 : acc0;
        const u32 labp = s ? labp1 : labp0;
#pragma unroll
        for (int r = 0; r < 4; ++r) {
          const int labi = (int)((labp >> (8 * r)) & 255u);
          const int irow = i_base + s * 16 + r;
          float s2 = 2.f * av[r];
          float e = __expf(s2);
          bool sm = (labj == labi);
          float dv = sm ? 0.f : e;
          float pv = (sm && (jrow != irow)) ? s2 : 0.f;
          den_acc[s][r] += dv;
          pos_acc[s][r] += pv;
          cd += dv; cp += pv;
        }
      }
      if (!diag) {
        cd += __shfl_xor(cd, 16, 64); cd += __shfl_xor(cd, 32, 64);
        cp += __shfl_xor(cp, 16, 64); cp += __shfl_xor(cp, 32, 64);
        if (kg4 == 0) {
          atomicAdd(&colden[t * 16 + l15], cd);
          atomicAdd(&colpos[t * 16 + l15], cp);
        }
      }
    }

    // row path: reduce across 16 cols (lanes with same kg4), 1 atomic/row
#pragma unroll
    for (int s = 0; s < 2; ++s)
#pragma unroll
      for (int r = 0; r < 4; ++r) {
        float dd = den_acc[s][r], pp = pos_acc[s][r];
#pragma unroll
        for (int m = 1; m < 16; m <<= 1) {
          dd += __shfl_xor(dd, m, 64);
          pp += __shfl_xor(pp, m, 64);
        }
        if (l15 == 0) {
          atomicAdd(&den[i_base + s * 16 + r], dd);
          atomicAdd(&pos[i_base + s * 16 + r], pp);
        }
      }

    // col path flush (off-diagonal): one atomic per col
    if (!diag) {
      __syncthreads();   // all waves' LDS col atomics done
      if (tid < TI) {
        atomicAdd(&den[jb + tid], colden[tid]);
        atomicAdd(&pos[jb + tid], colpos[tid]);
      }
    }
  }

  // ============ inline finalize: last-done block computes the scalar ======
  if (tid == 0) {
    __threadfence();             // release: this block's atomics visible
    stick = atomicAdd(done, 1);
  }
  __syncthreads();
  if (stick == GRID - 1) {
    if (tid == 0) __threadfence();   // acquire: invalidate stale lines
    __syncthreads();
    if (tid < 128) hist[tid] = 0;
    __syncthreads();
    for (int i = tid; i < N_ROWS; i += 256) atomicAdd(&hist[labels[i]], 1);
    __syncthreads();

    float num = 0.f, nnz = 0.f;
    for (int i = tid; i < N_ROWS; i += 256) {
      int c = hist[labels[i]] - 1;
      float dv = atomicAdd(&den[i], 0.f);   // device-coherent reads
      float pv = atomicAdd(&pos[i], 0.f);
      num += (float)c * logf(dv) - pv;
      nnz += (float)c;
    }
#pragma unroll
    for (int m = 1; m < 64; m <<= 1) {
      num += __shfl_xor(num, m, 64);
      nnz += __shfl_xor(nnz, m, 64);
    }
    if ((tid & 63) == 0) { sred[wv] = num; sred[4 + wv] = nnz; }
    __syncthreads();
    if (tid == 0) {
      float tn = sred[0] + sred[1] + sred[2] + sred[3];
      float tz = sred[4] + sred[5] + sred[6] + sred[7];
      out[0] = tn / (tz + EPS_DEN);
    }
  }
}

extern "C" void kernel_launch(void* const* d_in, const int* in_sizes, int n_in,
                              void* d_out, int out_size, void* d_ws, size_t ws_size,
                              hipStream_t stream) {
  const float* x = (const float*)d_in[0];
  const int* labels = (const int*)d_in[1];

  // ws: G fp8 (2MB) | den f32[4096] | pos f32[4096] | lab8 u8[4096]
  //   | acc2 f32[2] | done i32[1]
  u8* G = (u8*)d_ws;
  float* den = (float*)((char*)d_ws + (size_t)N_ROWS * DIM);
  float* pos = den + N_ROWS;
  u8* lab8 = (u8*)(pos + N_ROWS);
  float* acc2 = (float*)(lab8 + N_ROWS);
  int* done = (int*)(acc2 + 2);
  float* out = (float*)d_out;

  hipLaunchKernelGGL(k1_normalize, dim3(N_ROWS / 4), dim3(256), 0, stream,
                     x, labels, G, lab8, den, pos, acc2, done);
  hipLaunchKernelGGL(k2_fused, dim3(GRID), dim3(256), 0, stream,
                     G, lab8, labels, den, pos, acc2, done, out);
}

// Round 17
// 36.743 us; speedup vs baseline: 2.2117x; 1.3326x over previous
//
#include <hip/hip_runtime.h>
#include <hip/hip_bf16.h>
#include <hip/hip_fp8.h>

// ContrastiveLoss fused kernel for MI355X (gfx950).
//
// Math reduction (T=0.5):
//   f = x / max(||x||, 1e-8)   (rows)
//   s_ij = f_i . f_j
//   den_i = sum_{j: label_j != label_i} exp(2 s_ij)
//   loss  = sum_i [ c_i * log(den_i) - sum_{j same label, j != i} 2 s_ij ]
//           / (sum_i c_i + 1e-5),   c_i = count(label_i) - 1
//
// N=4096, D=512, labels in [0,100).
//
// Round 17: R14 structure (best, 36.8 us) with k2 at 8 WAVES PER BLOCK.
// R16 exposed k2 directly: active phase runs at 2 waves/SIMD (LDS 66.5KB
// -> 2 blocks/CU x 4 waves) -- too thin to overlap MFMA latency, ds_read
// latency, and the VALU epilogue (floor ~10-12 us, actual ~30). Same
// 128x128 tile, same 64 KB whole-tile staging, same zero-barrier loop,
// but 512 threads: each wave owns 16 i-rows (A = 1 group = 32 VGPR, two
// 8-deep MFMA chains), 4 waves/SIMD. R16's inline finalize reverted
// (single-block tail cost ~12 us): k3a 16-block finalize as in R14.

typedef float floatx4 __attribute__((ext_vector_type(4)));
typedef long lng2 __attribute__((ext_vector_type(2)));
typedef unsigned int u32;
typedef unsigned char u8;

#define N_ROWS 4096
#define DIM 512
#define GRPB 8192              // bytes per 16-row fp8 fragment group (16*512)
#define EPS_NORM 1e-8f
#define EPS_DEN 1e-5f
#define TI 128                 // tile size (rows and cols)
#define NT (N_ROWS / TI)       // 32 tiles
#define NPAIR (NT * (NT + 1) / 2)   // 528 blocks
#define NSLAB 8                // 8 slabs of 16 j-rows per tile

static __device__ inline void load_lds16(const char* g, char* l) {
  __builtin_amdgcn_global_load_lds(
      (const __attribute__((address_space(1))) void*)g,
      (__attribute__((address_space(3))) void*)l, 16, 0, 0);
}

// wave-per-row normalize + fp8 pack, fragment-major store; grid 1024 x 256.
// G layout (fp8): group g = row>>4 (8192 B), kt-pair p = kt>>1 (1024 B);
// consumer lane l = kq*16 + (row&15) holds fragment of kt at byte
// l*16 + (kt&1)*8, covering k = kt*32 + kq*8 .. +8.
__global__ void k1_normalize(const float* __restrict__ x,
                             const int* __restrict__ labels,
                             u8* __restrict__ G, u8* __restrict__ lab8,
                             float* __restrict__ den, float* __restrict__ pos,
                             float* __restrict__ acc2, int* __restrict__ done) {
  const int row = blockIdx.x * 4 + (threadIdx.x >> 6);
  const int lane = threadIdx.x & 63;
  const float4* src = reinterpret_cast<const float4*>(x + (size_t)row * DIM);
  float4 v0 = src[lane * 2];
  float4 v1 = src[lane * 2 + 1];
  float ss = v0.x*v0.x + v0.y*v0.y + v0.z*v0.z + v0.w*v0.w
           + v1.x*v1.x + v1.y*v1.y + v1.z*v1.z + v1.w*v1.w;
#pragma unroll
  for (int m = 1; m < 64; m <<= 1) ss += __shfl_xor(ss, m, 64);
  float scale = 1.f / fmaxf(sqrtf(ss), EPS_NORM);

  u32 lo = ((u32)__hip_fp8_e4m3(v0.x * scale).__x)
         | ((u32)__hip_fp8_e4m3(v0.y * scale).__x << 8)
         | ((u32)__hip_fp8_e4m3(v0.z * scale).__x << 16)
         | ((u32)__hip_fp8_e4m3(v0.w * scale).__x << 24);
  u32 hi = ((u32)__hip_fp8_e4m3(v1.x * scale).__x)
         | ((u32)__hip_fp8_e4m3(v1.y * scale).__x << 8)
         | ((u32)__hip_fp8_e4m3(v1.z * scale).__x << 16)
         | ((u32)__hip_fp8_e4m3(v1.w * scale).__x << 24);
  uint2 o; o.x = lo; o.y = hi;

  const int kt = lane >> 2;
  const int kq = lane & 3;
  char* dst = (char*)G + (size_t)(row >> 4) * GRPB + (kt >> 1) * 1024
            + (kq * 16 + (row & 15)) * 16 + (kt & 1) * 8;
  *reinterpret_cast<uint2*>(dst) = o;

  if (lane == 0) { den[row] = 0.f; pos[row] = 0.f; }
  if (lane == 1) lab8[row] = (u8)labels[row];
  if (blockIdx.x == 0 && threadIdx.x == 0) {
    acc2[0] = 0.f; acc2[1] = 0.f; done[0] = 0;
  }
}

// fused fp8 sim-GEMM + symmetric per-row/per-col reduction.
// 512 threads = 8 waves; whole 64 KB B tile staged once; zero-barrier loop.
__global__ __launch_bounds__(512, 4) void k2_fused(
    const u8* __restrict__ G, const u8* __restrict__ lab8,
    float* __restrict__ den, float* __restrict__ pos) {
  __shared__ u8 Bsh[64 * 1024];          // whole B tile: 64 chunks x 1 KB
  __shared__ int labj_sh[TI];
  __shared__ float colden[TI], colpos[TI];

  const char* Gb = (const char*)G;
  char* bshb = (char*)Bsh;

  // decode pair (ti, tj), ti <= tj, from blockIdx
  int b = blockIdx.x;
  int ti = 0, rem = NT;
  while (b >= rem) { b -= rem; ++ti; --rem; }
  const int tj = ti + b;
  const bool diag = (ti == tj);

  const int tid = threadIdx.x;
  const int wv = tid >> 6;                // 0..7
  const int lane = tid & 63;
  const int l15 = lane & 15;
  const int kg4 = lane >> 4;              // 0..3 (16-col groups)

  const int ib = ti * TI;
  const int jb = tj * TI;

  // stage the WHOLE B tile (64 KB = 64 chunks); wave wv stages chunks
  // wv*8 .. wv*8+7. Contiguous 1 KB src AND dst.
#pragma unroll
  for (int c = 0; c < 8; ++c) {
    const int chunk = wv * 8 + c;
    load_lds16(Gb + (size_t)(tj * 8 + (chunk >> 3)) * GRPB
                  + (chunk & 7) * 1024 + lane * 16,
               bshb + chunk * 1024 + lane * 16);
  }
  if (tid < TI) {
    labj_sh[tid] = lab8[jb + tid];
    colden[tid] = 0.f;
    colpos[tid] = 0.f;
  }

  // A fragments: 16 rows/wave = 1 fp8 fragment group -> 32 VGPRs.
  long a[16];
  {
    const char* ab = Gb + (size_t)(ti * 8 + wv) * GRPB + lane * 16;
#pragma unroll
    for (int q = 0; q < 8; ++q) {
      lng2 v = *reinterpret_cast<const lng2*>(ab + q * 1024);
      a[2 * q] = v.x; a[2 * q + 1] = v.y;
    }
  }
  // pin A in VGPRs (round-1 pathology: compiler sank loads into the loop)
#pragma unroll
  for (int kt = 0; kt < 16; ++kt)
    asm volatile("" : "+v"(a[kt]));

  // C/D layout (verified gfx950, dtype-independent): col = lane&15 (j),
  // row = kg4*4 + r (i). lane's 4 output rows: i_base + r.
  const int i_base = ib + wv * 16 + kg4 * 4;
  const u32 labp = *reinterpret_cast<const u32*>(lab8 + i_base);

  float den_acc[4] = {0.f, 0.f, 0.f, 0.f};
  float pos_acc[4] = {0.f, 0.f, 0.f, 0.f};

  __syncthreads();   // ONE drain: whole tile staged, labels + col accs ready

  // barrier-free main loop: 8 slabs; per slab two 8-deep MFMA chains
#pragma unroll
  for (int t = 0; t < NSLAB; ++t) {
    const int jrow = jb + t * 16 + l15;
    const int labj = labj_sh[t * 16 + l15];

    floatx4 acc_a = {0.f,0.f,0.f,0.f};
    floatx4 acc_b = {0.f,0.f,0.f,0.f};
    const char* bbase = bshb + t * 8192 + lane * 16;
#pragma unroll
    for (int q = 0; q < 8; ++q) {
      lng2 b2 = *reinterpret_cast<const lng2*>(bbase + q * 1024);
      acc_a = __builtin_amdgcn_mfma_f32_16x16x32_fp8_fp8(a[2*q],   b2.x, acc_a, 0, 0, 0);
      acc_b = __builtin_amdgcn_mfma_f32_16x16x32_fp8_fp8(a[2*q+1], b2.y, acc_b, 0, 0, 0);
    }

    float cd = 0.f, cp = 0.f;   // col partials for this 16-j slab
#pragma unroll
    for (int r = 0; r < 4; ++r) {
      const int labi = (int)((labp >> (8 * r)) & 255u);
      const int irow = i_base + r;
      float s2 = 2.f * (acc_a[r] + acc_b[r]);
      float e = __expf(s2);
      bool sm = (labj == labi);
      float dv = sm ? 0.f : e;
      float pv = (sm && (jrow != irow)) ? s2 : 0.f;
      den_acc[r] += dv;
      pos_acc[r] += pv;
      cd += dv; cp += pv;
    }
    if (!diag) {
      // reduce col partials across the 4 kg groups (lanes sharing l15)
      cd += __shfl_xor(cd, 16, 64); cd += __shfl_xor(cd, 32, 64);
      cp += __shfl_xor(cp, 16, 64); cp += __shfl_xor(cp, 32, 64);
      if (kg4 == 0) {
        atomicAdd(&colden[t * 16 + l15], cd);
        atomicAdd(&colpos[t * 16 + l15], cp);
      }
    }
  }

  // row path: reduce across 16 cols (lanes with same kg4), 1 atomic/row
#pragma unroll
  for (int r = 0; r < 4; ++r) {
    float dd = den_acc[r], pp = pos_acc[r];
#pragma unroll
    for (int m = 1; m < 16; m <<= 1) {
      dd += __shfl_xor(dd, m, 64);
      pp += __shfl_xor(pp, m, 64);
    }
    if (l15 == 0) {
      atomicAdd(&den[i_base + r], dd);
      atomicAdd(&pos[i_base + r], pp);
    }
  }

  // col path flush (off-diagonal): one atomic per col
  if (!diag) {
    __syncthreads();   // all waves' LDS col atomics done
    if (tid < TI) {
      atomicAdd(&den[jb + tid], colden[tid]);
      atomicAdd(&pos[jb + tid], colpos[tid]);
    }
  }
}

// per-row finalize + scalar write: 16 blocks x 256 threads; last-done
// block (device atomics) computes the output. (Proven in R14: absmax 0.)
__global__ void k3a(const float* __restrict__ den, const float* __restrict__ pos,
                    const int* __restrict__ labels, float* __restrict__ acc2,
                    int* __restrict__ done, float* __restrict__ out) {
  __shared__ int hist[128];
  __shared__ float sn[4], sz[4];
  const int tid = threadIdx.x;
  if (tid < 128) hist[tid] = 0;
  __syncthreads();
  for (int i = tid; i < N_ROWS; i += 256) atomicAdd(&hist[labels[i]], 1);
  __syncthreads();

  const int row = blockIdx.x * 256 + tid;
  int c = hist[labels[row]] - 1;
  float num = (float)c * logf(den[row]) - pos[row];
  float nnz = (float)c;
#pragma unroll
  for (int m = 1; m < 64; m <<= 1) {
    num += __shfl_xor(num, m, 64);
    nnz += __shfl_xor(nnz, m, 64);
  }
  if ((tid & 63) == 0) { sn[tid >> 6] = num; sz[tid >> 6] = nnz; }
  __syncthreads();
  if (tid == 0) {
    atomicAdd(&acc2[0], sn[0] + sn[1] + sn[2] + sn[3]);
    atomicAdd(&acc2[1], sz[0] + sz[1] + sz[2] + sz[3]);
    __threadfence();
    int old = atomicAdd(done, 1);
    if (old == 15) {
      float tn = atomicAdd(&acc2[0], 0.f);   // coherent device-scope read
      float tz = atomicAdd(&acc2[1], 0.f);
      out[0] = tn / (tz + EPS_DEN);
    }
  }
}

extern "C" void kernel_launch(void* const* d_in, const int* in_sizes, int n_in,
                              void* d_out, int out_size, void* d_ws, size_t ws_size,
                              hipStream_t stream) {
  const float* x = (const float*)d_in[0];
  const int* labels = (const int*)d_in[1];

  // ws: G fp8 (2MB) | den f32[4096] | pos f32[4096] | lab8 u8[4096]
  //   | acc2 f32[2] | done i32[1]
  u8* G = (u8*)d_ws;
  float* den = (float*)((char*)d_ws + (size_t)N_ROWS * DIM);
  float* pos = den + N_ROWS;
  u8* lab8 = (u8*)(pos + N_ROWS);
  float* acc2 = (float*)(lab8 + N_ROWS);
  int* done = (int*)(acc2 + 2);
  float* out = (float*)d_out;

  hipLaunchKernelGGL(k1_normalize, dim3(N_ROWS / 4), dim3(256), 0, stream,
                     x, labels, G, lab8, den, pos, acc2, done);
  hipLaunchKernelGGL(k2_fused, dim3(NPAIR), dim3(512), 0, stream,
                     G, lab8, den, pos);
  hipLaunchKernelGGL(k3a, dim3(16), dim3(256), 0, stream,
                     den, pos, labels, acc2, done, out);
}